// Round 1
// baseline (1997.044 us; speedup 1.0000x reference)
//
#include <hip/hip_runtime.h>
#include <math.h>

#define DIV_UP(a,b) (((a)+(b)-1)/(b))

static constexpr int Bb = 4, Tt = 256, Mm = 512, Dd = 1024, Vv = 50257;
static constexpr int NN = Bb * Tt;   // 1024 flattened (b,t) rows

// ---------------------------------------------------------------------------
// Generic tiled fp32 GEMM.
//   BT=false: C[i,j] = sum_k A[i,k] * B[k,j]   (B row-major KxN)
//   BT=true : C[i,j] = sum_k A[i,k] * B[j,k]   (B row-major NxK, dot-product)
// A can be split at column `ksplit`: k >= ksplit reads A2[i, k-ksplit] (lda2).
// ACT: 0 none, 1 tanh. HAS_BIAS adds bias[j]. Batched via blockIdx.z strides.
// Rows (M dim) must be divisible by BM; K divisible by BK and 4; cols guarded.
// ---------------------------------------------------------------------------
template<int BM, int BN, int BK, bool BT, int ACT, bool HAS_BIAS>
__launch_bounds__(256)
__global__ void gemm_f32(const float* __restrict__ A,
                         const float* __restrict__ A2, int ksplit, int lda2,
                         const float* __restrict__ B,
                         const float* __restrict__ bias,
                         float* __restrict__ C,
                         int Ncols, int K, int lda, int ldb, int ldc,
                         long sAb, long sBb, long sCb)
{
    constexpr int TM = BM / 16;
    constexpr int TN = BN / 16;
    __shared__ float As[BK][BM + 4];   // +4 pad: keeps 16B alignment, breaks bank aliasing
    __shared__ float Bs[BK][BN + 4];

    const int tid = threadIdx.x;
    const int tx = tid & 15;
    const int ty = tid >> 4;
    const int bz = blockIdx.z;
    const int i0 = blockIdx.y * BM;
    const int j0 = blockIdx.x * BN;

    const float* Ab  = A + (long)bz * sAb;
    const float* Bp  = B + (long)bz * sBb;

    float acc[TM][TN];
#pragma unroll
    for (int i = 0; i < TM; ++i)
#pragma unroll
        for (int j = 0; j < TN; ++j) acc[i][j] = 0.0f;

    for (int k0 = 0; k0 < K; k0 += BK) {
        const float* Asrc = Ab;
        int acol = k0, ldae = lda;
        if (k0 >= ksplit) { Asrc = A2; acol = k0 - ksplit; ldae = lda2; }

        // ---- A tile (BM x BK) -> transposed LDS As[k][m]
#pragma unroll
        for (int l = 0; l < (BM * BK) / 1024; ++l) {
            int idx = tid + l * 256;
            int row = idx >> 2;
            int kq  = (idx & 3) * 4;
            float4 av = *(const float4*)&Asrc[(long)(i0 + row) * ldae + acol + kq];
            As[kq + 0][row] = av.x;
            As[kq + 1][row] = av.y;
            As[kq + 2][row] = av.z;
            As[kq + 3][row] = av.w;
        }
        // ---- B tile
        if (BT) {
#pragma unroll
            for (int l = 0; l < (BN * BK) / 1024; ++l) {
                int idx = tid + l * 256;
                int row = idx >> 2;          // j within tile
                int kq  = (idx & 3) * 4;
                float4 bv = make_float4(0.f, 0.f, 0.f, 0.f);
                if (j0 + row < Ncols)
                    bv = *(const float4*)&Bp[(long)(j0 + row) * ldb + k0 + kq];
                Bs[kq + 0][row] = bv.x;
                Bs[kq + 1][row] = bv.y;
                Bs[kq + 2][row] = bv.z;
                Bs[kq + 3][row] = bv.w;
            }
        } else {
#pragma unroll
            for (int l = 0; l < (BN * BK) / 1024; ++l) {
                int idx  = tid + l * 256;
                int krow = idx / (BN / 4);
                int c4   = (idx % (BN / 4)) * 4;
                float4 bv = make_float4(0.f, 0.f, 0.f, 0.f);
                if (j0 + c4 + 3 < Ncols) {
                    bv = *(const float4*)&Bp[(long)(k0 + krow) * ldb + j0 + c4];
                } else {
                    float t[4];
#pragma unroll
                    for (int q = 0; q < 4; ++q)
                        t[q] = (j0 + c4 + q < Ncols)
                             ? Bp[(long)(k0 + krow) * ldb + j0 + c4 + q] : 0.f;
                    bv = make_float4(t[0], t[1], t[2], t[3]);
                }
                *(float4*)&Bs[krow][c4] = bv;
            }
        }
        __syncthreads();
#pragma unroll
        for (int kk = 0; kk < BK; ++kk) {
            float a[TM], b[TN];
#pragma unroll
            for (int p = 0; p < TM / 4; ++p) {
                float4 v = *(const float4*)&As[kk][ty * TM + p * 4];
                a[p*4+0] = v.x; a[p*4+1] = v.y; a[p*4+2] = v.z; a[p*4+3] = v.w;
            }
#pragma unroll
            for (int p = 0; p < TN / 4; ++p) {
                float4 v = *(const float4*)&Bs[kk][tx * TN + p * 4];
                b[p*4+0] = v.x; b[p*4+1] = v.y; b[p*4+2] = v.z; b[p*4+3] = v.w;
            }
#pragma unroll
            for (int i = 0; i < TM; ++i)
#pragma unroll
                for (int j = 0; j < TN; ++j)
                    acc[i][j] = fmaf(a[i], b[j], acc[i][j]);
        }
        __syncthreads();
    }

    float* Cb = C + (long)bz * sCb;
    const bool vec_ok = ((ldc & 3) == 0);
#pragma unroll
    for (int i = 0; i < TM; ++i) {
        int row = i0 + ty * TM + i;
#pragma unroll
        for (int p = 0; p < TN / 4; ++p) {
            int col = j0 + tx * TN + p * 4;
            float v[4];
#pragma unroll
            for (int q = 0; q < 4; ++q) {
                float x = acc[i][p * 4 + q];
                if (HAS_BIAS && (col + q < Ncols)) x += bias[col + q];
                if (ACT == 1) x = tanhf(x);
                v[q] = x;
            }
            if (vec_ok && (col + 3 < Ncols)) {
                *(float4*)&Cb[(long)row * ldc + col] = make_float4(v[0], v[1], v[2], v[3]);
            } else {
#pragma unroll
                for (int q = 0; q < 4; ++q)
                    if (col + q < Ncols) Cb[(long)row * ldc + col + q] = v[q];
            }
        }
    }
}

// ---- masked softmax over M=512, in place; attn[m>=len]=0 ---------------------
__global__ void softmax_rows(float* __restrict__ s, const int* __restrict__ msl)
{
    __shared__ float red[256];
    const int row = blockIdx.x;
    const int b   = row / Tt;
    const int len = msl[b];
    float* p = s + (long)row * Mm;
    const int tid = threadIdx.x;

    float v[2], mx = -INFINITY;
#pragma unroll
    for (int q = 0; q < 2; ++q) {
        int m = tid + q * 256;
        v[q] = (m < len) ? p[m] : -INFINITY;
        mx = fmaxf(mx, v[q]);
    }
    red[tid] = mx; __syncthreads();
    for (int off = 128; off > 0; off >>= 1) {
        if (tid < off) red[tid] = fmaxf(red[tid], red[tid + off]);
        __syncthreads();
    }
    mx = red[0]; __syncthreads();

    float e[2], sm = 0.f;
#pragma unroll
    for (int q = 0; q < 2; ++q) {
        int m = tid + q * 256;
        e[q] = (m < len) ? expf(v[q] - mx) : 0.f;
        sm += e[q];
    }
    red[tid] = sm; __syncthreads();
    for (int off = 128; off > 0; off >>= 1) {
        if (tid < off) red[tid] += red[tid + off];
        __syncthreads();
    }
    const float inv = 1.0f / red[0];
#pragma unroll
    for (int q = 0; q < 2; ++q) p[tid + q * 256] = e[q] * inv;
}

// ---- p_gen[row] = sigmoid(dot(dwa[row], Wg) + bg) ---------------------------
__global__ void pgen_kernel(const float* __restrict__ dwa, const float* __restrict__ Wg,
                            const float* __restrict__ bg, float* __restrict__ pg)
{
    __shared__ float red[256];
    const int row = blockIdx.x;
    const float* x = dwa + (long)row * Dd;
    const int tid = threadIdx.x;
    float s = 0.f;
#pragma unroll
    for (int q = 0; q < 4; ++q) {
        int d = tid + q * 256;
        s += x[d] * Wg[d];
    }
    red[tid] = s; __syncthreads();
    for (int off = 128; off > 0; off >>= 1) {
        if (tid < off) red[tid] += red[tid + off];
        __syncthreads();
    }
    if (tid == 0) pg[row] = 1.0f / (1.0f + expf(-(red[0] + bg[0])));
}

// ---- per-row online max / sum(exp) over V ----------------------------------
__global__ void rowstats_kernel(const float* __restrict__ logits,
                                float* __restrict__ rowmax, float* __restrict__ rowsum)
{
    __shared__ float rm[256], rs[256];
    const int row = blockIdx.x;
    const float* p = logits + (long)row * Vv;
    const int tid = threadIdx.x;
    float mx = -INFINITY, sm = 0.f;
    for (int v = tid; v < Vv; v += 256) {
        float x = p[v];
        float nm = fmaxf(mx, x);
        sm = sm * expf(mx - nm) + expf(x - nm);
        mx = nm;
    }
    rm[tid] = mx; rs[tid] = sm; __syncthreads();
    for (int off = 128; off > 0; off >>= 1) {
        if (tid < off) {
            float m1 = rm[tid], s1 = rs[tid];
            float m2 = rm[tid + off], s2 = rs[tid + off];
            float nm = fmaxf(m1, m2);
            rm[tid] = nm;
            rs[tid] = s1 * expf(m1 - nm) + s2 * expf(m2 - nm);
        }
        __syncthreads();
    }
    if (tid == 0) { rowmax[row] = rm[0]; rowsum[row] = rs[0]; }
}

// ---- out = exp(l - max)/sum * p_gen  (in place) -----------------------------
__global__ void scale_kernel(float* __restrict__ out, const float* __restrict__ rowmax,
                             const float* __restrict__ rowsum, const float* __restrict__ pg)
{
    const int row = blockIdx.y;
    const int v0  = blockIdx.x * 1024 + threadIdx.x;
    const float mx  = rowmax[row];
    const float inv = pg[row] / rowsum[row];
    float* p = out + (long)row * Vv;
#pragma unroll
    for (int q = 0; q < 4; ++q) {
        int v = v0 + q * 256;
        if (v < Vv) p[v] = expf(p[v] - mx) * inv;
    }
}

// ---- scatter-add copy probs -------------------------------------------------
__global__ void scatter_kernel(float* __restrict__ out, const float* __restrict__ attn,
                               const float* __restrict__ pg, const int* __restrict__ ids,
                               const int* __restrict__ msl)
{
    const int row = blockIdx.x;
    const int b   = row / Tt;
    const int len = msl[b];
    const float c = 1.0f - pg[row];
    const float* a  = attn + (long)row * Mm;
    const int* idb  = ids + (long)b * Mm;
    for (int m = threadIdx.x; m < len; m += 256) {
        atomicAdd(&out[(long)row * Vv + idb[m]], a[m] * c);
    }
}

// ---- out = log(out) ---------------------------------------------------------
__global__ void log_kernel(float* __restrict__ out)
{
    const int row = blockIdx.y;
    const int v0  = blockIdx.x * 1024 + threadIdx.x;
    float* p = out + (long)row * Vv;
#pragma unroll
    for (int q = 0; q < 4; ++q) {
        int v = v0 + q * 256;
        if (v < Vv) p[v] = logf(p[v]);
    }
}

extern "C" void kernel_launch(void* const* d_in, const int* in_sizes, int n_in,
                              void* d_out, int out_size, void* d_ws, size_t ws_size,
                              hipStream_t stream)
{
    const float* dec = (const float*)d_in[0];
    const float* mem = (const float*)d_in[1];
    const int*   msl = (const int*)d_in[2];
    const int*   ids = (const int*)d_in[3];
    const float* Wc  = (const float*)d_in[4];
    // d_in[5] = b_copy: adds a per-(b,t) constant to all scores -> softmax-invariant; skip.
    const float* Wd  = (const float*)d_in[6];
    const float* bd  = (const float*)d_in[7];
    const float* Wg  = (const float*)d_in[8];
    const float* bg  = (const float*)d_in[9];
    const float* Wo  = (const float*)d_in[10];
    const float* bo  = (const float*)d_in[11];

    float* out = (float*)d_out;
    // ws: only data that must survive the big logits GEMM (~2.1 MB)
    float* ws     = (float*)d_ws;
    float* attn   = ws;                          // NN*Mm
    float* pg     = attn + (size_t)NN * Mm;      // NN
    float* rowmax = pg + NN;                     // NN
    float* rowsum = rowmax + NN;                 // NN
    // d_out doubles as scratch before the logits GEMM overwrites all of it
    float* dec_proj = out;                       // NN*Dd
    float* attn_out = out + (size_t)NN * Dd;     // NN*Dd
    float* dwa      = out + (size_t)2 * NN * Dd; // NN*Dd

    // 1. dec_proj = dec @ W_copy                (NN x Dd x Dd)
    gemm_f32<64,64,16,false,0,false><<<dim3(Dd/64, NN/64, 1), 256, 0, stream>>>(
        dec, dec, Dd, Dd, Wc, nullptr, dec_proj, Dd, Dd, Dd, Dd, Dd, 0, 0, 0);

    // 2. scores[b] = dec_proj[b] @ mem[b]^T     (batched NT, Tt x Mm x Dd)
    gemm_f32<64,64,16,true,0,false><<<dim3(Mm/64, Tt/64, Bb), 256, 0, stream>>>(
        dec_proj, dec_proj, Dd, Dd, mem, nullptr, attn, Mm, Dd, Dd, Dd, Mm,
        (long)Tt*Dd, (long)Mm*Dd, (long)Tt*Mm);

    // 3. masked softmax (mask folded here; b_copy shift already dropped)
    softmax_rows<<<NN, 256, 0, stream>>>(attn, msl);

    // 4. attn_out[b] = attn[b] @ mem[b]         (batched NN, Tt x Dd x Mm)
    gemm_f32<64,64,16,false,0,false><<<dim3(Dd/64, Tt/64, Bb), 256, 0, stream>>>(
        attn, attn, Mm, Mm, mem, nullptr, attn_out, Dd, Mm, Mm, Dd, Dd,
        (long)Tt*Mm, (long)Mm*Dd, (long)Tt*Dd);

    // 5. dwa = tanh([dec|attn_out] @ W_dec^T + b_dec)   (split-A NT, K=2048)
    gemm_f32<64,64,16,true,1,true><<<dim3(Dd/64, NN/64, 1), 256, 0, stream>>>(
        dec, attn_out, Dd, Dd, Wd, bd, dwa, Dd, 2*Dd, Dd, 2*Dd, Dd, 0, 0, 0);

    // 6. p_gen
    pgen_kernel<<<NN, 256, 0, stream>>>(dwa, Wg, bg, pg);

    // 7. logits = dec @ W_out^T + b_out  -> d_out (105 GFLOP, the hot kernel)
    gemm_f32<128,128,16,true,0,true><<<dim3(DIV_UP(Vv,128), NN/128, 1), 256, 0, stream>>>(
        dec, dec, Dd, Dd, Wo, bo, out, Vv, Dd, Dd, Dd, Vv, 0, 0, 0);

    // 8. per-row max / sumexp
    rowstats_kernel<<<NN, 256, 0, stream>>>(out, rowmax, rowsum);

    // 9. gen_probs = softmax * p_gen (in place)
    scale_kernel<<<dim3(DIV_UP(Vv,1024), NN), 256, 0, stream>>>(out, rowmax, rowsum, pg);

    // 10. scatter-add copy probs
    scatter_kernel<<<NN, 256, 0, stream>>>(out, attn, pg, ids, msl);

    // 11. log
    log_kernel<<<dim3(DIV_UP(Vv,1024), NN), 256, 0, stream>>>(out);
}